// Round 9
// baseline (1014.905 us; speedup 1.0000x reference)
//
#include <hip/hip_runtime.h>
#include <hip/hip_bf16.h>
#include <math.h>

// Problem constants
#define BB 8
#define NN 1024
#define BN 8192
#define D_IN 128
#define HH 256
#define LL 4
#define NHD 8
#define DH 32
#define EE 131072
#define EPSV 1e-5f

typedef unsigned short u16;
typedef unsigned int u32;
typedef __attribute__((ext_vector_type(8))) short bf16x8;
typedef __attribute__((ext_vector_type(4))) float f32x4;

__device__ __forceinline__ float gelu_erf(float x) {
    return 0.5f * x * (1.0f + erff(x * 0.70710678118654752f));
}

__device__ __forceinline__ u16 f2bf(float v) {
    __hip_bfloat16 b = __float2bfloat16(v);   // RNE
    return *reinterpret_cast<u16*>(&b);
}

__device__ __forceinline__ float bf2f(u16 u) {
    u32 x = ((u32)u) << 16;
    return __builtin_bit_cast(float, x);
}

__device__ __forceinline__ u32 pack2bf(float lo, float hi) {
    return ((u32)f2bf(hi) << 16) | (u32)f2bf(lo);
}

__device__ __forceinline__ float exp2_fast(float x) {   // raw v_exp_f32 (2^x)
    float r;
    asm("v_exp_f32 %0, %1" : "=v"(r) : "v"(x));
    return r;
}

// ---------------- all fp32->bf16 casts in ONE kernel (segments hardcoded) ----
__global__ __launch_bounds__(256) void cast_all_kernel(
        const float* s0, const float* s1, const float* s2, const float* s3,
        const float* s4, const float* s5, const float* s6, const float* s7,
        u16* d0, u16* d1, u16* d2, u16* d3, u16* d4, u16* d5, u16* d6, u16* d7) {
    int blk = blockIdx.x;
    const float* s; u16* d; int base;
    if      (blk < 1024) { s = s0; d = d0; base = 0; }
    else if (blk < 1056) { s = s1; d = d1; base = 1024; }
    else if (blk < 1312) { s = s2; d = d2; base = 1056; }
    else if (blk < 2080) { s = s3; d = d3; base = 1312; }
    else if (blk < 2336) { s = s4; d = d4; base = 2080; }
    else if (blk < 3360) { s = s5; d = d5; base = 2336; }
    else if (blk < 4384) { s = s6; d = d6; base = 3360; }
    else                 { s = s7; d = d7; base = 4384; }
    int i = (blk - base) * 256 + threadIdx.x;
    float4 v = ((const float4*)s)[i];
    ushort4 o;
    o.x = f2bf(v.x); o.y = f2bf(v.y); o.z = f2bf(v.z); o.w = f2bf(v.w);
    ((ushort4*)d)[i] = o;
}

// ---------------- CSR build ----------------
__global__ __launch_bounds__(256) void hist_kernel(const int* __restrict__ edge_row,
                                                   int* __restrict__ counts) {
    int e = blockIdx.x * 256 + threadIdx.x;
    atomicAdd(&counts[edge_row[e]], 1);
}

__global__ __launch_bounds__(256) void prefix_kernel(const int* __restrict__ counts,
                                                     int* __restrict__ row_start,
                                                     int* __restrict__ cursor) {
    __shared__ int lds[256];
    int t = threadIdx.x;
    int local[32];
    int s = 0;
#pragma unroll
    for (int i = 0; i < 32; ++i) { local[i] = counts[t * 32 + i]; s += local[i]; }
    lds[t] = s;
    __syncthreads();
    for (int off = 1; off < 256; off <<= 1) {
        int v = (t >= off) ? lds[t - off] : 0;
        __syncthreads();
        lds[t] += v;
        __syncthreads();
    }
    int excl = (t == 0) ? 0 : lds[t - 1];
#pragma unroll
    for (int i = 0; i < 32; ++i) {
        int c = local[i];
        row_start[t * 32 + i] = excl;
        cursor[t * 32 + i] = excl;
        excl += c;
    }
    if (t == 255) row_start[8192] = excl;
}

__global__ __launch_bounds__(256) void scatter_kernel(const int* __restrict__ edge_row,
                                                      int* __restrict__ cursor,
                                                      int* __restrict__ csr_e) {
    int e = blockIdx.x * 256 + threadIdx.x;
    int r = edge_row[e];
    int pos = atomicAdd(&cursor[r], 1);
    csr_e[pos] = e;
}

// ---------------- fused GCN gather + residual + BN stats ----------------
// h[r][c] = (h[r][c]*sc+sh) + gelu(sum_e val*t1b[col_e][c]); atomic col stats.
// Sa==nullptr -> identity transform (layer 0). Grid 1024 x 8 rows, c = tid.
__global__ __launch_bounds__(256) void gather_bn_kernel(const u16* __restrict__ t1b,
                                                        const int* __restrict__ row_start,
                                                        const int* __restrict__ csr_e,
                                                        const int* __restrict__ edge_col,
                                                        const float* __restrict__ edge_val,
                                                        float* __restrict__ h,
                                                        const float* __restrict__ Sa,
                                                        const float* __restrict__ Qa,
                                                        const float* __restrict__ ga,
                                                        const float* __restrict__ ba,
                                                        float* __restrict__ So,
                                                        float* __restrict__ Qo) {
    int c = threadIdx.x;
    float sc = 1.f, sh = 0.f;
    if (Sa) {
        float mean = Sa[c] * (1.f / 8192.f);
        float var = Qa[c] * (1.f / 8192.f) - mean * mean;
        float rs = rsqrtf(var + EPSV);
        sc = ga[c] * rs;
        sh = ba[c] - mean * sc;
    }
    int r0 = blockIdx.x * 8;
    float s = 0.f, q = 0.f;
#pragma unroll
    for (int i = 0; i < 8; ++i) {
        int r = r0 + i;
        int p0 = row_start[r], p1 = row_start[r + 1];
        float a = 0.f;
        for (int p = p0; p < p1; ++p) {
            int e = csr_e[p];                       // uniform -> scalar
            float v = edge_val[e];
            a += v * bf2f(t1b[(size_t)edge_col[e] * HH + c]);
        }
        size_t idx = (size_t)r * HH + c;
        float nv = h[idx] * sc + sh + gelu_erf(a);
        h[idx] = nv;
        s += nv; q += nv * nv;
    }
    atomicAdd(&So[c], s);
    atomicAdd(&Qo[c], q);
}

// ---------------- bf16 MFMA GEMM 128x64 tile ----------------
// OUTMODE: 0=f32 C, 1=bf16 C, 2=residual into h: nv=(h*scr+shr)+acc+bias, +stats
// NORMA:   0=A is bf16 ; 1=A is fp32 h, per-channel norm (Sa==nullptr -> identity)
#define SWZ(row, c8) ((c8) ^ (((row) & 7) << 3))
template <int EPI, int OUTMODE, int NORMA>
__global__ __launch_bounds__(256) void gemm_mfma(
        const void* __restrict__ Ain, const u16* __restrict__ W,
        const float* __restrict__ bias, void* __restrict__ Cout,
        int M, int K, int N,
        const float* __restrict__ Sa, const float* __restrict__ Qa,
        const float* __restrict__ ga, const float* __restrict__ ba,
        const float* __restrict__ Sr, const float* __restrict__ Qr,
        const float* __restrict__ gr, const float* __restrict__ br,
        float* __restrict__ So, float* __restrict__ Qo,
        float* __restrict__ Zs, float* __restrict__ Zq) {
    __shared__ u16 As[128][64];
    __shared__ u16 Ws[64][64];
    int t = threadIdx.x;
    if (Zs != nullptr && blockIdx.x == 0 && blockIdx.y == 0) {
        Zs[t] = 0.f; Zq[t] = 0.f;      // zero next BN stats slot (no concurrent writer)
    }
    int bm = blockIdx.y * 128, bn = blockIdx.x * 64;
    int wid = t >> 6, lane = t & 63;
    int wr = wid >> 1, wc = wid & 1;
    int lr = lane & 15, lg = lane >> 4;

    f32x4 zero = {0.f, 0.f, 0.f, 0.f};
    f32x4 acc[4][2];
#pragma unroll
    for (int mi = 0; mi < 4; ++mi)
#pragma unroll
        for (int ni = 0; ni < 2; ++ni) acc[mi][ni] = zero;

    int sr = t >> 3;
    int c8 = (t & 7) * 8;

    for (int k0 = 0; k0 < K; k0 += 64) {
        __syncthreads();
        if (NORMA) {
            float scj[8], shj[8];
            if (Sa) {
#pragma unroll
                for (int j = 0; j < 8; ++j) {
                    int ch = k0 + c8 + j;
                    float mean = Sa[ch] * (1.f / 8192.f);
                    float var = Qa[ch] * (1.f / 8192.f) - mean * mean;
                    float rs = rsqrtf(var + EPSV);
                    scj[j] = ga[ch] * rs;
                    shj[j] = ba[ch] - mean * scj[j];
                }
            } else {
#pragma unroll
                for (int j = 0; j < 8; ++j) { scj[j] = 1.f; shj[j] = 0.f; }
            }
#pragma unroll
            for (int p = 0; p < 4; ++p) {
                int row = sr + p * 32;
                const float* src = (const float*)Ain + (size_t)(bm + row) * K + k0 + c8;
                float4 a0 = *(const float4*)src;
                float4 a1 = *(const float4*)(src + 4);
                union { u16 a[8]; int4 v; } pk;
                pk.a[0] = f2bf(a0.x * scj[0] + shj[0]);
                pk.a[1] = f2bf(a0.y * scj[1] + shj[1]);
                pk.a[2] = f2bf(a0.z * scj[2] + shj[2]);
                pk.a[3] = f2bf(a0.w * scj[3] + shj[3]);
                pk.a[4] = f2bf(a1.x * scj[4] + shj[4]);
                pk.a[5] = f2bf(a1.y * scj[5] + shj[5]);
                pk.a[6] = f2bf(a1.z * scj[6] + shj[6]);
                pk.a[7] = f2bf(a1.w * scj[7] + shj[7]);
                *(int4*)&As[row][SWZ(row, c8)] = pk.v;
            }
        } else {
#pragma unroll
            for (int p = 0; p < 4; ++p) {
                int row = sr + p * 32;
                const u16* src = (const u16*)Ain + (size_t)(bm + row) * K + k0 + c8;
                *(int4*)&As[row][SWZ(row, c8)] = *(const int4*)src;
            }
        }
#pragma unroll
        for (int p = 0; p < 2; ++p) {
            int row = sr + p * 32;
            const u16* src = W + (size_t)(bn + row) * K + k0 + c8;
            *(int4*)&Ws[row][SWZ(row, c8)] = *(const int4*)src;
        }
        __syncthreads();
#pragma unroll
        for (int kk = 0; kk < 2; ++kk) {
            bf16x8 af[4], bf[2];
#pragma unroll
            for (int mi = 0; mi < 4; ++mi) {
                int row = wr * 64 + mi * 16 + lr;
                af[mi] = *(const bf16x8*)&As[row][SWZ(row, kk * 32 + lg * 8)];
            }
#pragma unroll
            for (int ni = 0; ni < 2; ++ni) {
                int row = wc * 32 + ni * 16 + lr;
                bf[ni] = *(const bf16x8*)&Ws[row][SWZ(row, kk * 32 + lg * 8)];
            }
#pragma unroll
            for (int mi = 0; mi < 4; ++mi)
#pragma unroll
                for (int ni = 0; ni < 2; ++ni)
                    acc[mi][ni] = __builtin_amdgcn_mfma_f32_16x16x32_bf16(af[mi], bf[ni], acc[mi][ni], 0, 0, 0);
        }
    }

    if (OUTMODE == 2) {
#pragma unroll
        for (int ni = 0; ni < 2; ++ni) {
            int col = bn + wc * 32 + ni * 16 + lr;
            float mean = Sr[col] * (1.f / 8192.f);
            float var = Qr[col] * (1.f / 8192.f) - mean * mean;
            float rs = rsqrtf(var + EPSV);
            float scr = gr[col] * rs;
            float shr = br[col] - mean * scr + bias[col];
            float s = 0.f, q = 0.f;
#pragma unroll
            for (int mi = 0; mi < 4; ++mi) {
#pragma unroll
                for (int r = 0; r < 4; ++r) {
                    int row = bm + wr * 64 + mi * 16 + lg * 4 + r;
                    float* hp = (float*)Cout + (size_t)row * N + col;
                    float nv = (*hp) * scr + shr + acc[mi][ni][r];
                    *hp = nv;
                    s += nv; q += nv * nv;
                }
            }
            s += __shfl_xor(s, 16); s += __shfl_xor(s, 32);
            q += __shfl_xor(q, 16); q += __shfl_xor(q, 32);
            if (lg == 0) {
                atomicAdd(&So[col], s);
                atomicAdd(&Qo[col], q);
            }
        }
    } else {
#pragma unroll
        for (int ni = 0; ni < 2; ++ni) {
            int col = bn + wc * 32 + ni * 16 + lr;
            float bj = bias ? bias[col] : 0.f;
#pragma unroll
            for (int mi = 0; mi < 4; ++mi) {
#pragma unroll
                for (int r = 0; r < 4; ++r) {
                    int row = bm + wr * 64 + mi * 16 + lg * 4 + r;
                    float v = acc[mi][ni][r] + bj;
                    if (EPI == 1) v = gelu_erf(v);
                    if (OUTMODE == 1)
                        ((u16*)Cout)[(size_t)row * N + col] = f2bf(v);
                    else
                        ((float*)Cout)[(size_t)row * N + col] = v;
                }
            }
        }
    }
}

// ---------------- bf16 MFMA GEMM 128x128 tile (N multiple of 128) ----------------
template <int EPI, int OUTBF, int NORMA>
__global__ __launch_bounds__(256) void gemm_mfma2(
        const void* __restrict__ Ain, const u16* __restrict__ W,
        const float* __restrict__ bias, void* __restrict__ Cout,
        int M, int K, int N,
        const float* __restrict__ Sa, const float* __restrict__ Qa,
        const float* __restrict__ ga, const float* __restrict__ ba,
        float* __restrict__ Zs, float* __restrict__ Zq) {
    __shared__ u16 As[128][64];
    __shared__ u16 Ws[128][64];
    int t = threadIdx.x;
    if (Zs != nullptr && blockIdx.x == 0 && blockIdx.y == 0) {
        Zs[t] = 0.f; Zq[t] = 0.f;
    }
    int bm = blockIdx.y * 128, bn = blockIdx.x * 128;
    int wid = t >> 6, lane = t & 63;
    int wr = wid >> 1, wc = wid & 1;
    int lr = lane & 15, lg = lane >> 4;

    f32x4 zero = {0.f, 0.f, 0.f, 0.f};
    f32x4 acc[4][4];
#pragma unroll
    for (int mi = 0; mi < 4; ++mi)
#pragma unroll
        for (int ni = 0; ni < 4; ++ni) acc[mi][ni] = zero;

    int sr = t >> 3;
    int c8 = (t & 7) * 8;

    for (int k0 = 0; k0 < K; k0 += 64) {
        __syncthreads();
        if (NORMA) {
            float scj[8], shj[8];
            if (Sa) {
#pragma unroll
                for (int j = 0; j < 8; ++j) {
                    int ch = k0 + c8 + j;
                    float mean = Sa[ch] * (1.f / 8192.f);
                    float var = Qa[ch] * (1.f / 8192.f) - mean * mean;
                    float rs = rsqrtf(var + EPSV);
                    scj[j] = ga[ch] * rs;
                    shj[j] = ba[ch] - mean * scj[j];
                }
            } else {
#pragma unroll
                for (int j = 0; j < 8; ++j) { scj[j] = 1.f; shj[j] = 0.f; }
            }
#pragma unroll
            for (int p = 0; p < 4; ++p) {
                int row = sr + p * 32;
                const float* src = (const float*)Ain + (size_t)(bm + row) * K + k0 + c8;
                float4 a0 = *(const float4*)src;
                float4 a1 = *(const float4*)(src + 4);
                union { u16 a[8]; int4 v; } pk;
                pk.a[0] = f2bf(a0.x * scj[0] + shj[0]);
                pk.a[1] = f2bf(a0.y * scj[1] + shj[1]);
                pk.a[2] = f2bf(a0.z * scj[2] + shj[2]);
                pk.a[3] = f2bf(a0.w * scj[3] + shj[3]);
                pk.a[4] = f2bf(a1.x * scj[4] + shj[4]);
                pk.a[5] = f2bf(a1.y * scj[5] + shj[5]);
                pk.a[6] = f2bf(a1.z * scj[6] + shj[6]);
                pk.a[7] = f2bf(a1.w * scj[7] + shj[7]);
                *(int4*)&As[row][SWZ(row, c8)] = pk.v;
            }
        } else {
#pragma unroll
            for (int p = 0; p < 4; ++p) {
                int row = sr + p * 32;
                const u16* src = (const u16*)Ain + (size_t)(bm + row) * K + k0 + c8;
                *(int4*)&As[row][SWZ(row, c8)] = *(const int4*)src;
            }
        }
#pragma unroll
        for (int p = 0; p < 4; ++p) {
            int row = sr + p * 32;
            const u16* srcW = W + (size_t)(bn + row) * K + k0 + c8;
            *(int4*)&Ws[row][SWZ(row, c8)] = *(const int4*)srcW;
        }
        __syncthreads();
#pragma unroll
        for (int kk = 0; kk < 2; ++kk) {
            bf16x8 af[4], bf[4];
#pragma unroll
            for (int mi = 0; mi < 4; ++mi) {
                int row = wr * 64 + mi * 16 + lr;
                af[mi] = *(const bf16x8*)&As[row][SWZ(row, kk * 32 + lg * 8)];
            }
#pragma unroll
            for (int ni = 0; ni < 4; ++ni) {
                int row = wc * 64 + ni * 16 + lr;
                bf[ni] = *(const bf16x8*)&Ws[row][SWZ(row, kk * 32 + lg * 8)];
            }
#pragma unroll
            for (int mi = 0; mi < 4; ++mi)
#pragma unroll
                for (int ni = 0; ni < 4; ++ni)
                    acc[mi][ni] = __builtin_amdgcn_mfma_f32_16x16x32_bf16(af[mi], bf[ni], acc[mi][ni], 0, 0, 0);
        }
    }

#pragma unroll
    for (int ni = 0; ni < 4; ++ni) {
        int col = bn + wc * 64 + ni * 16 + lr;
        float bj = bias ? bias[col] : 0.f;
#pragma unroll
        for (int mi = 0; mi < 4; ++mi) {
#pragma unroll
            for (int r = 0; r < 4; ++r) {
                int row = bm + wr * 64 + mi * 16 + lg * 4 + r;
                float v = acc[mi][ni][r] + bj;
                if (EPI == 1) v = gelu_erf(v);
                if (OUTBF)
                    ((u16*)Cout)[(size_t)row * N + col] = f2bf(v);
                else
                    ((float*)Cout)[(size_t)row * N + col] = v;
            }
        }
    }
}

// small K=8 GEMM accumulate: h += pe @ W_pe^T + b_pe (fp32 only)
__global__ __launch_bounds__(256) void pe_add_kernel(const float* __restrict__ pe,
                                                     const float* __restrict__ Wpe,
                                                     const float* __restrict__ bpe,
                                                     float* __restrict__ h) {
    __shared__ float Ws[8][256];
    int t = threadIdx.x;
    for (int i = t; i < 2048; i += 256) Ws[i & 7][i >> 3] = Wpe[i];
    __syncthreads();
    int w = t >> 6, lane = t & 63;
    int r = blockIdx.x * 4 + w;
    const float* pr = pe + r * 8;
    float p[8];
#pragma unroll
    for (int k = 0; k < 8; ++k) p[k] = pr[k];
    int c0 = lane * 4;
    float4 hv = *(float4*)&h[(size_t)r * HH + c0];
    float o0 = hv.x + bpe[c0 + 0], o1 = hv.y + bpe[c0 + 1];
    float o2 = hv.z + bpe[c0 + 2], o3 = hv.w + bpe[c0 + 3];
#pragma unroll
    for (int k = 0; k < 8; ++k) {
        o0 += p[k] * Ws[k][c0 + 0];
        o1 += p[k] * Ws[k][c0 + 1];
        o2 += p[k] * Ws[k][c0 + 2];
        o3 += p[k] * Ws[k][c0 + 3];
    }
    float4 ov; ov.x = o0; ov.y = o1; ov.z = o2; ov.w = o3;
    *(float4*)&h[(size_t)r * HH + c0] = ov;
}

// ---------------- V transpose: qkv V-part -> vT[b][h][d][key] ----------------
__global__ __launch_bounds__(256) void vtrans_kernel(const u16* __restrict__ qkv,
                                                     u16* __restrict__ vT) {
    __shared__ u16 Ls[64][64];
    int bid = blockIdx.x;
    int kt = bid & 15;
    int head = (bid >> 4) & 7;
    int b = bid >> 7;
    int t = threadIdx.x;
    int key_l = t >> 2, blkS = t & 3;
    const u16* src = qkv + (size_t)(b * NN + kt * 64 + key_l) * 768 + 512 + head * DH + blkS * 8;
    int sb = (blkS ^ (key_l & 7) ^ ((key_l >> 3) & 7)) * 8;
    *(int4*)&Ls[key_l][sb] = *(const int4*)src;
    __syncthreads();
    int d = t >> 3, kc = t & 7;
    union { u16 a[8]; int4 v; } tmp;
#pragma unroll
    for (int j = 0; j < 8; ++j) {
        int col = (((d >> 3) ^ j ^ kc) << 3) | (d & 7);
        tmp.a[j] = Ls[kc * 8 + j][col];
    }
    u16* dst = vT + (size_t)((b * 8 + head) * 32 + d) * NN + kt * 64 + kc * 8;
    *(int4*)dst = tmp.v;
}

// ---------------- MFMA flash attention (exp2-domain softmax, defer-max) ------
__global__ __launch_bounds__(256) void attn_mfma_kernel(const u16* __restrict__ qkv,
                                                        const u16* __restrict__ vT,
                                                        u16* __restrict__ o) {
    __shared__ __align__(16) u16 Ks[64][40];
    __shared__ __align__(16) u16 Vt[32][72];
    __shared__ __align__(16) u16 Ot[64][40];
    int bid = blockIdx.x;
    int qt = bid & 15;
    int head = (bid >> 4) & 7;
    int b = bid >> 7;
    int t = threadIdx.x;
    int w = t >> 6, lane = t & 63;
    int lr = lane & 15, lg = lane >> 4;

    // q scale = 1/sqrt(32) * log2(e)  (exp2-domain softmax)
    bf16x8 qf;
    {
        const u16* qsrc = qkv + (size_t)(b * NN + qt * 64 + w * 16 + lr) * 768 + head * DH + lg * 8;
        bf16x8 raw = *(const bf16x8*)qsrc;
#pragma unroll
        for (int j = 0; j < 8; ++j) {
            float f = bf2f((u16)raw[j]) * 0.25503530f;
            qf[j] = (short)f2bf(f);
        }
    }

    f32x4 zero = {0.f, 0.f, 0.f, 0.f};
    f32x4 oacc[2] = {zero, zero};
    float m = -1e30f, l = 0.f;

    int srow = t >> 2, sc8 = (t & 3) * 8;
    int vd = t >> 3, vc8 = (t & 7) * 8;
    const u16* kbase = qkv + (size_t)(b * NN) * 768 + 256 + head * DH + sc8;
    const u16* vbase = vT + (size_t)((b * 8 + head) * 32 + vd) * NN + vc8;

    int srcA = ((lg & 1) << 5) + lr;
    int srcB = srcA + 16;
    int hi = lg >> 1;

    for (int k0 = 0; k0 < NN; k0 += 64) {
        __syncthreads();
        *(int4*)&Ks[srow][sc8] = *(const int4*)(kbase + (size_t)(k0 + srow) * 768);
        *(int4*)&Vt[vd][vc8] = *(const int4*)(vbase + k0);
        __syncthreads();

        f32x4 st[4];
#pragma unroll
        for (int kt = 0; kt < 4; ++kt) {
            bf16x8 kf = *(const bf16x8*)&Ks[kt * 16 + lr][lg * 8];
            st[kt] = __builtin_amdgcn_mfma_f32_16x16x32_bf16(kf, qf, zero, 0, 0, 0);
        }

        float tm = -1e30f;
#pragma unroll
        for (int kt = 0; kt < 4; ++kt)
#pragma unroll
            for (int r = 0; r < 4; ++r) tm = fmaxf(tm, st[kt][r]);
        tm = fmaxf(tm, __shfl_xor(tm, 16));
        tm = fmaxf(tm, __shfl_xor(tm, 32));
        // defer-max (T13): rescale only when max grows by >8 (log2 units; P <= 256)
        if (__any(tm > m + 8.0f)) {
            float mn = fmaxf(m, tm);
            float corr = exp2_fast(m - mn);
            l *= corr;
#pragma unroll
            for (int dh = 0; dh < 2; ++dh)
#pragma unroll
                for (int r = 0; r < 4; ++r) oacc[dh][r] *= corr;
            m = mn;
        }

        float ps = 0.f;
        u32 pw0[4], pw1[4];
#pragma unroll
        for (int kt = 0; kt < 4; ++kt) {
            float p0 = exp2_fast(st[kt][0] - m);
            float p1 = exp2_fast(st[kt][1] - m);
            float p2 = exp2_fast(st[kt][2] - m);
            float p3 = exp2_fast(st[kt][3] - m);
            ps += (p0 + p1) + (p2 + p3);
            pw0[kt] = pack2bf(p0, p1);
            pw1[kt] = pack2bf(p2, p3);
        }
        ps += __shfl_xor(ps, 16);
        ps += __shfl_xor(ps, 32);
        l += ps;

#pragma unroll
        for (int c = 0; c < 2; ++c) {
            u32 w0a = (u32)__shfl((int)pw0[c * 2], srcA);
            u32 w0b = (u32)__shfl((int)pw0[c * 2 + 1], srcA);
            u32 w1a = (u32)__shfl((int)pw1[c * 2], srcA);
            u32 w1b = (u32)__shfl((int)pw1[c * 2 + 1], srcA);
            u32 w2a = (u32)__shfl((int)pw0[c * 2], srcB);
            u32 w2b = (u32)__shfl((int)pw0[c * 2 + 1], srcB);
            u32 w3a = (u32)__shfl((int)pw1[c * 2], srcB);
            u32 w3b = (u32)__shfl((int)pw1[c * 2 + 1], srcB);
            union { bf16x8 v; u32 u[4]; } pf;
            pf.u[0] = hi ? w0b : w0a;
            pf.u[1] = hi ? w1b : w1a;
            pf.u[2] = hi ? w2b : w2a;
            pf.u[3] = hi ? w3b : w3a;
#pragma unroll
            for (int dh = 0; dh < 2; ++dh) {
                bf16x8 vf = *(const bf16x8*)&Vt[dh * 16 + lr][c * 32 + lg * 8];
                oacc[dh] = __builtin_amdgcn_mfma_f32_16x16x32_bf16(vf, pf.v, oacc[dh], 0, 0, 0);
            }
        }
    }

    float inv = 1.f / l;
    __syncthreads();
#pragma unroll
    for (int dh = 0; dh < 2; ++dh)
#pragma unroll
        for (int r = 0; r < 4; ++r)
            Ot[w * 16 + lr][dh * 16 + lg * 4 + r] = f2bf(oacc[dh][r] * inv);
    __syncthreads();
    {
        int orow = t >> 2, oc8 = (t & 3) * 8;
        u16* dst = o + (size_t)(b * NN + qt * 64 + orow) * HH + head * DH + oc8;
        *(int4*)dst = *(const int4*)&Ot[orow][oc8];
    }
}

// ---------------- head2 ----------------
__global__ __launch_bounds__(256) void head2_kernel(const float* __restrict__ g1,
                                                    const float* __restrict__ W2,
                                                    const float* __restrict__ b2,
                                                    float* __restrict__ out) {
    __shared__ float w[128];
    int t = threadIdx.x;
    if (t < 128) w[t] = W2[t];
    __syncthreads();
    int r = blockIdx.x * 256 + t;
    float s = b2[0];
    const float* row = g1 + (size_t)r * 128;
#pragma unroll
    for (int k = 0; k < 128; k += 4) {
        float4 v = *(const float4*)&row[k];
        s += v.x * w[k] + v.y * w[k + 1] + v.z * w[k + 2] + v.w * w[k + 3];
    }
    out[r] = 1.f / (1.f + __expf(-s));
}

extern "C" void kernel_launch(void* const* d_in, const int* in_sizes, int n_in,
                              void* d_out, int out_size, void* d_ws, size_t ws_size,
                              hipStream_t stream) {
    const float* x        = (const float*)d_in[0];
    const int*   edge_row = (const int*)d_in[1];
    const int*   edge_col = (const int*)d_in[2];
    const float* edge_val = (const float*)d_in[3];
    const float* pe       = (const float*)d_in[4];
    const float* W_in     = (const float*)d_in[5];
    const float* b_in     = (const float*)d_in[6];
    const float* W_pe     = (const float*)d_in[7];
    const float* b_pe     = (const float*)d_in[8];
    const float* gcn_W    = (const float*)d_in[9];
    const float* attn_in_W  = (const float*)d_in[10];
    const float* attn_in_b  = (const float*)d_in[11];
    const float* attn_out_W = (const float*)d_in[12];
    const float* attn_out_b = (const float*)d_in[13];
    const float* bn_g     = (const float*)d_in[14];
    const float* bn_b     = (const float*)d_in[15];
    const float* ffn_W1   = (const float*)d_in[16];
    const float* ffn_b1   = (const float*)d_in[17];
    const float* ffn_W2   = (const float*)d_in[18];
    const float* ffn_b2   = (const float*)d_in[19];
    const float* head_W1  = (const float*)d_in[20];
    const float* head_b1  = (const float*)d_in[21];
    const float* head_W2  = (const float*)d_in[22];
    const float* head_b2  = (const float*)d_in[23];
    float* out = (float*)d_out;

    float* w = (float*)d_ws;
    float* h    = w; w += 2097152;       // (8192,256) fp32 residual stream (pre-norm)
    float* buf1 = w; w += 8388608;       // 32MB multi-use
    int* counts    = (int*)w; w += 8192; // zeroed by memset
    float* bnstats = w; w += 1024;       // [2 slots][S 256 | Q 256], zeroed by same memset
    int* row_start = (int*)w; w += 8224;
    int* cursor    = (int*)w; w += 8192;
    int* csr_e     = (int*)w; w += 131072;
    // bf16 region
    u16* xb   = (u16*)w;
    u16* aob  = xb + 1048576;
    u16* wbWin = aob + 2097152;
    u16* wbGcn = wbWin + 32768;
    u16* wbAin = wbGcn + 262144;
    u16* wbAout = wbAin + 786432;
    u16* wbF1  = wbAout + 262144;
    u16* wbF2  = wbF1 + 1048576;
    u16* wbH1  = wbF2 + 1048576;
    // aliases inside buf1 (time-disjoint)
    u16* t1b  = (u16*)buf1;
    u16* qkvb = (u16*)buf1;
    u16* midb = (u16*)buf1;
    u16* vT   = (u16*)buf1 + 12582912;

    auto Sp = [&](int k) { return bnstats + (k & 1) * 512; };
    auto Qp = [&](int k) { return bnstats + (k & 1) * 512 + 256; };
    const float* NF = nullptr;

    // CSR build (+ zero both BN stats slots via the same memset)
    hipMemsetAsync(counts, 0, (8192 + 1024) * sizeof(int), stream);
    hist_kernel<<<512, 256, 0, stream>>>(edge_row, counts);
    prefix_kernel<<<1, 256, 0, stream>>>(counts, row_start, cursor);
    scatter_kernel<<<512, 256, 0, stream>>>(edge_row, cursor, csr_e);

    // all weight/x casts in one launch
    cast_all_kernel<<<4416, 256, 0, stream>>>(
        x, W_in, gcn_W, attn_in_W, attn_out_W, ffn_W1, ffn_W2, head_W1,
        xb, wbWin, wbGcn, wbAin, wbAout, wbF1, wbF2, wbH1);

    // input projection (bf16 A, fp32 out -> h) + PE add
    gemm_mfma<0, 0, 0><<<dim3(4, 64), 256, 0, stream>>>(xb, wbWin, b_in, h, BN, D_IN, HH,
        NF, NF, NF, NF, NF, NF, NF, NF, nullptr, nullptr, nullptr, nullptr);
    pe_add_kernel<<<2048, 256, 0, stream>>>(pe, W_pe, b_pe, h);

    for (int l = 0; l < LL; ++l) {
        int k1 = 3 * l, k2 = 3 * l + 1, k3 = 3 * l + 2;
        const float* SaP = (l == 0) ? nullptr : Sp(k1 - 1);
        const float* QaP = (l == 0) ? nullptr : Qp(k1 - 1);
        const float* gP  = (l == 0) ? bn_g : bn_g + (k1 - 1) * 256;
        const float* bP  = (l == 0) ? bn_b : bn_b + (k1 - 1) * 256;

        // GCN linear: t1b = norm_{BN(k1-1)}(h) @ gcn_W^T (bf16 out); zeroes slot k1
        gemm_mfma<0, 1, 1><<<dim3(4, 64), 256, 0, stream>>>(h, wbGcn + l * 65536, nullptr, t1b, BN, HH, HH,
            SaP, QaP, gP, bP, NF, NF, NF, NF, nullptr, nullptr, Sp(k1), Qp(k1));
        // gather + gelu + residual(norm) + BN(k1) stats
        gather_bn_kernel<<<1024, 256, 0, stream>>>(t1b, row_start, csr_e, edge_col, edge_val, h,
            SaP, QaP, gP, bP, Sp(k1), Qp(k1));

        // qkv = norm_{BN(k1)}(h) @ Wqkv^T (bf16); zeroes slot k2
        gemm_mfma2<0, 1, 1><<<dim3(6, 64), 256, 0, stream>>>(h, wbAin + l * 196608, attn_in_b + l * 768, qkvb, BN, HH, 768,
            Sp(k1), Qp(k1), bn_g + k1 * 256, bn_b + k1 * 256, Sp(k2), Qp(k2));
        vtrans_kernel<<<1024, 256, 0, stream>>>(qkvb, vT);
        attn_mfma_kernel<<<1024, 256, 0, stream>>>(qkvb, vT, aob);
        // out-proj: h = norm_{BN(k1)}(h) + aob @ Waout^T + b ; accumulates BN(k2) stats
        gemm_mfma<0, 2, 0><<<dim3(4, 64), 256, 0, stream>>>(aob, wbAout + l * 65536, attn_out_b + l * 256, h, BN, HH, HH,
            NF, NF, NF, NF, Sp(k1), Qp(k1), bn_g + k1 * 256, bn_b + k1 * 256, Sp(k2), Qp(k2), nullptr, nullptr);

        // FFN: mid = gelu(norm_{BN(k2)}(h) @ W1^T) (bf16); zeroes slot k3
        gemm_mfma2<1, 1, 1><<<dim3(8, 64), 256, 0, stream>>>(h, wbF1 + l * 262144, ffn_b1 + l * 1024, midb, BN, HH, 1024,
            Sp(k2), Qp(k2), bn_g + k2 * 256, bn_b + k2 * 256, Sp(k3), Qp(k3));
        // ffn2: h = norm_{BN(k2)}(h) + mid @ W2^T + b ; accumulates BN(k3) stats
        gemm_mfma<0, 2, 0><<<dim3(4, 64), 256, 0, stream>>>(midb, wbF2 + l * 262144, ffn_b2 + l * 256, h, BN, 1024, HH,
            NF, NF, NF, NF, Sp(k2), Qp(k2), bn_g + k2 * 256, bn_b + k2 * 256, Sp(k3), Qp(k3), nullptr, nullptr);
    }

    // head: g1 = gelu(norm_{BN11}(h) @ head_W1^T) fp32 ; out = sigmoid(g1 @ W2^T + b2)
    gemm_mfma<1, 0, 1><<<dim3(2, 64), 256, 0, stream>>>(h, wbH1, head_b1, buf1, BN, HH, 128,
        Sp(11), Qp(11), bn_g + 11 * 256, bn_b + 11 * 256, NF, NF, NF, NF, nullptr, nullptr, nullptr, nullptr);
    head2_kernel<<<32, 256, 0, stream>>>(buf1, head_W2, head_b2, out);
}

// Round 10
// 832.078 us; speedup vs baseline: 1.2197x; 1.2197x over previous
//
#include <hip/hip_runtime.h>
#include <hip/hip_bf16.h>
#include <math.h>

// Problem constants
#define BB 8
#define NN 1024
#define BN 8192
#define D_IN 128
#define HH 256
#define LL 4
#define NHD 8
#define DH 32
#define EE 131072
#define EPSV 1e-5f

typedef unsigned short u16;
typedef unsigned int u32;
typedef __attribute__((ext_vector_type(8))) short bf16x8;
typedef __attribute__((ext_vector_type(4))) float f32x4;

__device__ __forceinline__ float gelu_erf(float x) {
    return 0.5f * x * (1.0f + erff(x * 0.70710678118654752f));
}

__device__ __forceinline__ u16 f2bf(float v) {
    __hip_bfloat16 b = __float2bfloat16(v);   // RNE
    return *reinterpret_cast<u16*>(&b);
}

__device__ __forceinline__ float bf2f(u16 u) {
    u32 x = ((u32)u) << 16;
    return __builtin_bit_cast(float, x);
}

__device__ __forceinline__ u32 pack2bf(float lo, float hi) {
    return ((u32)f2bf(hi) << 16) | (u32)f2bf(lo);
}

__device__ __forceinline__ float exp2_fast(float x) {   // raw v_exp_f32 (2^x)
    float r;
    asm("v_exp_f32 %0, %1" : "=v"(r) : "v"(x));
    return r;
}

// ---------------- all fp32->bf16 casts in ONE kernel (segments hardcoded) ----
__global__ __launch_bounds__(256) void cast_all_kernel(
        const float* s0, const float* s1, const float* s2, const float* s3,
        const float* s4, const float* s5, const float* s6, const float* s7,
        u16* d0, u16* d1, u16* d2, u16* d3, u16* d4, u16* d5, u16* d6, u16* d7) {
    int blk = blockIdx.x;
    const float* s; u16* d; int base;
    if      (blk < 1024) { s = s0; d = d0; base = 0; }
    else if (blk < 1056) { s = s1; d = d1; base = 1024; }
    else if (blk < 1312) { s = s2; d = d2; base = 1056; }
    else if (blk < 2080) { s = s3; d = d3; base = 1312; }
    else if (blk < 2336) { s = s4; d = d4; base = 2080; }
    else if (blk < 3360) { s = s5; d = d5; base = 2336; }
    else if (blk < 4384) { s = s6; d = d6; base = 3360; }
    else                 { s = s7; d = d7; base = 4384; }
    int i = (blk - base) * 256 + threadIdx.x;
    float4 v = ((const float4*)s)[i];
    ushort4 o;
    o.x = f2bf(v.x); o.y = f2bf(v.y); o.z = f2bf(v.z); o.w = f2bf(v.w);
    ((ushort4*)d)[i] = o;
}

// ---------------- CSR build ----------------
__global__ __launch_bounds__(256) void hist_kernel(const int* __restrict__ edge_row,
                                                   int* __restrict__ counts) {
    int e = blockIdx.x * 256 + threadIdx.x;
    atomicAdd(&counts[edge_row[e]], 1);
}

__global__ __launch_bounds__(256) void prefix_kernel(const int* __restrict__ counts,
                                                     int* __restrict__ row_start,
                                                     int* __restrict__ cursor) {
    __shared__ int lds[256];
    int t = threadIdx.x;
    int local[32];
    int s = 0;
#pragma unroll
    for (int i = 0; i < 32; ++i) { local[i] = counts[t * 32 + i]; s += local[i]; }
    lds[t] = s;
    __syncthreads();
    for (int off = 1; off < 256; off <<= 1) {
        int v = (t >= off) ? lds[t - off] : 0;
        __syncthreads();
        lds[t] += v;
        __syncthreads();
    }
    int excl = (t == 0) ? 0 : lds[t - 1];
#pragma unroll
    for (int i = 0; i < 32; ++i) {
        int c = local[i];
        row_start[t * 32 + i] = excl;
        cursor[t * 32 + i] = excl;
        excl += c;
    }
    if (t == 255) row_start[8192] = excl;
}

__global__ __launch_bounds__(256) void scatter_kernel(const int* __restrict__ edge_row,
                                                      int* __restrict__ cursor,
                                                      int* __restrict__ csr_e) {
    int e = blockIdx.x * 256 + threadIdx.x;
    int r = edge_row[e];
    int pos = atomicAdd(&cursor[r], 1);
    csr_e[pos] = e;
}

// ---------------- GCN gather (bf16 t1, wave-per-row): buf2 = gelu(spmm) ------
__global__ __launch_bounds__(256) void gcn_gather_kernel(const u16* __restrict__ t1b,
                                                         const int* __restrict__ row_start,
                                                         const int* __restrict__ csr_e,
                                                         const int* __restrict__ edge_col,
                                                         const float* __restrict__ edge_val,
                                                         float* __restrict__ outb) {
    int wave = threadIdx.x >> 6;
    int lane = threadIdx.x & 63;
    int r = blockIdx.x * 4 + wave;
    float a0 = 0.f, a1 = 0.f, a2 = 0.f, a3 = 0.f;
    int p0 = row_start[r], p1 = row_start[r + 1];
    for (int p = p0; p < p1; ++p) {
        int e = csr_e[p];
        int c = edge_col[e];
        float v = edge_val[e];
        ushort4 sv = *(const ushort4*)&t1b[(size_t)c * HH + lane * 4];
        a0 += v * bf2f(sv.x); a1 += v * bf2f(sv.y);
        a2 += v * bf2f(sv.z); a3 += v * bf2f(sv.w);
    }
    float4 g;
    g.x = gelu_erf(a0); g.y = gelu_erf(a1); g.z = gelu_erf(a2); g.w = gelu_erf(a3);
    *(float4*)&outb[(size_t)r * HH + lane * 4] = g;
}

// ---------------- BN phase A: h = norm_prev(h) + add, atomic col stats -------
// Sa==nullptr -> identity norm (layer 0). Grid 256, c = tid, 32 rows/block.
__global__ __launch_bounds__(256) void bn_reduce_norm_kernel(float* __restrict__ h,
                                                             const float* __restrict__ add,
                                                             const float* __restrict__ Sa,
                                                             const float* __restrict__ Qa,
                                                             const float* __restrict__ ga,
                                                             const float* __restrict__ ba,
                                                             float* __restrict__ So,
                                                             float* __restrict__ Qo) {
    int c = threadIdx.x;
    float sc = 1.f, sh = 0.f;
    if (Sa) {
        float mean = Sa[c] * (1.f / 8192.f);
        float var = Qa[c] * (1.f / 8192.f) - mean * mean;
        float rs = rsqrtf(var + EPSV);
        sc = ga[c] * rs;
        sh = ba[c] - mean * sc;
    }
    int r0 = blockIdx.x * 32;
    float s = 0.f, q = 0.f;
#pragma unroll 4
    for (int i = 0; i < 32; ++i) {
        size_t idx = (size_t)(r0 + i) * HH + c;
        float nv = h[idx] * sc + sh + add[idx];
        h[idx] = nv;
        s += nv; q += nv * nv;
    }
    atomicAdd(&So[c], s);
    atomicAdd(&Qo[c], q);
}

// ---------------- bf16 MFMA GEMM 128x64 tile ----------------
// OUTMODE: 0=f32 C, 1=bf16 C, 2=residual into h: nv=(h*scr+shr)+acc+bias, +stats
// NORMA:   0=A is bf16 ; 1=A is fp32 h, per-channel norm (Sa==nullptr -> identity)
#define SWZ(row, c8) ((c8) ^ (((row) & 7) << 3))
template <int EPI, int OUTMODE, int NORMA>
__global__ __launch_bounds__(256) void gemm_mfma(
        const void* __restrict__ Ain, const u16* __restrict__ W,
        const float* __restrict__ bias, void* __restrict__ Cout,
        int M, int K, int N,
        const float* __restrict__ Sa, const float* __restrict__ Qa,
        const float* __restrict__ ga, const float* __restrict__ ba,
        const float* __restrict__ Sr, const float* __restrict__ Qr,
        const float* __restrict__ gr, const float* __restrict__ br,
        float* __restrict__ So, float* __restrict__ Qo,
        float* __restrict__ Zs, float* __restrict__ Zq) {
    __shared__ u16 As[128][64];
    __shared__ u16 Ws[64][64];
    int t = threadIdx.x;
    if (Zs != nullptr && blockIdx.x == 0 && blockIdx.y == 0) {
        Zs[t] = 0.f; Zq[t] = 0.f;      // zero next BN stats slot (no concurrent writer)
    }
    int bm = blockIdx.y * 128, bn = blockIdx.x * 64;
    int wid = t >> 6, lane = t & 63;
    int wr = wid >> 1, wc = wid & 1;
    int lr = lane & 15, lg = lane >> 4;

    f32x4 zero = {0.f, 0.f, 0.f, 0.f};
    f32x4 acc[4][2];
#pragma unroll
    for (int mi = 0; mi < 4; ++mi)
#pragma unroll
        for (int ni = 0; ni < 2; ++ni) acc[mi][ni] = zero;

    int sr = t >> 3;
    int c8 = (t & 7) * 8;

    for (int k0 = 0; k0 < K; k0 += 64) {
        __syncthreads();
        if (NORMA) {
            float scj[8], shj[8];
            if (Sa) {
#pragma unroll
                for (int j = 0; j < 8; ++j) {
                    int ch = k0 + c8 + j;
                    float mean = Sa[ch] * (1.f / 8192.f);
                    float var = Qa[ch] * (1.f / 8192.f) - mean * mean;
                    float rs = rsqrtf(var + EPSV);
                    scj[j] = ga[ch] * rs;
                    shj[j] = ba[ch] - mean * scj[j];
                }
            } else {
#pragma unroll
                for (int j = 0; j < 8; ++j) { scj[j] = 1.f; shj[j] = 0.f; }
            }
#pragma unroll
            for (int p = 0; p < 4; ++p) {
                int row = sr + p * 32;
                const float* src = (const float*)Ain + (size_t)(bm + row) * K + k0 + c8;
                float4 a0 = *(const float4*)src;
                float4 a1 = *(const float4*)(src + 4);
                union { u16 a[8]; int4 v; } pk;
                pk.a[0] = f2bf(a0.x * scj[0] + shj[0]);
                pk.a[1] = f2bf(a0.y * scj[1] + shj[1]);
                pk.a[2] = f2bf(a0.z * scj[2] + shj[2]);
                pk.a[3] = f2bf(a0.w * scj[3] + shj[3]);
                pk.a[4] = f2bf(a1.x * scj[4] + shj[4]);
                pk.a[5] = f2bf(a1.y * scj[5] + shj[5]);
                pk.a[6] = f2bf(a1.z * scj[6] + shj[6]);
                pk.a[7] = f2bf(a1.w * scj[7] + shj[7]);
                *(int4*)&As[row][SWZ(row, c8)] = pk.v;
            }
        } else {
#pragma unroll
            for (int p = 0; p < 4; ++p) {
                int row = sr + p * 32;
                const u16* src = (const u16*)Ain + (size_t)(bm + row) * K + k0 + c8;
                *(int4*)&As[row][SWZ(row, c8)] = *(const int4*)src;
            }
        }
#pragma unroll
        for (int p = 0; p < 2; ++p) {
            int row = sr + p * 32;
            const u16* src = W + (size_t)(bn + row) * K + k0 + c8;
            *(int4*)&Ws[row][SWZ(row, c8)] = *(const int4*)src;
        }
        __syncthreads();
#pragma unroll
        for (int kk = 0; kk < 2; ++kk) {
            bf16x8 af[4], bf[2];
#pragma unroll
            for (int mi = 0; mi < 4; ++mi) {
                int row = wr * 64 + mi * 16 + lr;
                af[mi] = *(const bf16x8*)&As[row][SWZ(row, kk * 32 + lg * 8)];
            }
#pragma unroll
            for (int ni = 0; ni < 2; ++ni) {
                int row = wc * 32 + ni * 16 + lr;
                bf[ni] = *(const bf16x8*)&Ws[row][SWZ(row, kk * 32 + lg * 8)];
            }
#pragma unroll
            for (int mi = 0; mi < 4; ++mi)
#pragma unroll
                for (int ni = 0; ni < 2; ++ni)
                    acc[mi][ni] = __builtin_amdgcn_mfma_f32_16x16x32_bf16(af[mi], bf[ni], acc[mi][ni], 0, 0, 0);
        }
    }

    if (OUTMODE == 2) {
#pragma unroll
        for (int ni = 0; ni < 2; ++ni) {
            int col = bn + wc * 32 + ni * 16 + lr;
            float mean = Sr[col] * (1.f / 8192.f);
            float var = Qr[col] * (1.f / 8192.f) - mean * mean;
            float rs = rsqrtf(var + EPSV);
            float scr = gr[col] * rs;
            float shr = br[col] - mean * scr + bias[col];
            float s = 0.f, q = 0.f;
#pragma unroll
            for (int mi = 0; mi < 4; ++mi) {
#pragma unroll
                for (int r = 0; r < 4; ++r) {
                    int row = bm + wr * 64 + mi * 16 + lg * 4 + r;
                    float* hp = (float*)Cout + (size_t)row * N + col;
                    float nv = (*hp) * scr + shr + acc[mi][ni][r];
                    *hp = nv;
                    s += nv; q += nv * nv;
                }
            }
            s += __shfl_xor(s, 16); s += __shfl_xor(s, 32);
            q += __shfl_xor(q, 16); q += __shfl_xor(q, 32);
            if (lg == 0) {
                atomicAdd(&So[col], s);
                atomicAdd(&Qo[col], q);
            }
        }
    } else {
#pragma unroll
        for (int ni = 0; ni < 2; ++ni) {
            int col = bn + wc * 32 + ni * 16 + lr;
            float bj = bias ? bias[col] : 0.f;
#pragma unroll
            for (int mi = 0; mi < 4; ++mi) {
#pragma unroll
                for (int r = 0; r < 4; ++r) {
                    int row = bm + wr * 64 + mi * 16 + lg * 4 + r;
                    float v = acc[mi][ni][r] + bj;
                    if (EPI == 1) v = gelu_erf(v);
                    if (OUTMODE == 1)
                        ((u16*)Cout)[(size_t)row * N + col] = f2bf(v);
                    else
                        ((float*)Cout)[(size_t)row * N + col] = v;
                }
            }
        }
    }
}

// ---------------- bf16 MFMA GEMM 128x128 tile (N multiple of 128) ----------------
template <int EPI, int OUTBF, int NORMA>
__global__ __launch_bounds__(256) void gemm_mfma2(
        const void* __restrict__ Ain, const u16* __restrict__ W,
        const float* __restrict__ bias, void* __restrict__ Cout,
        int M, int K, int N,
        const float* __restrict__ Sa, const float* __restrict__ Qa,
        const float* __restrict__ ga, const float* __restrict__ ba,
        float* __restrict__ Zs, float* __restrict__ Zq) {
    __shared__ u16 As[128][64];
    __shared__ u16 Ws[128][64];
    int t = threadIdx.x;
    if (Zs != nullptr && blockIdx.x == 0 && blockIdx.y == 0) {
        Zs[t] = 0.f; Zq[t] = 0.f;
    }
    int bm = blockIdx.y * 128, bn = blockIdx.x * 128;
    int wid = t >> 6, lane = t & 63;
    int wr = wid >> 1, wc = wid & 1;
    int lr = lane & 15, lg = lane >> 4;

    f32x4 zero = {0.f, 0.f, 0.f, 0.f};
    f32x4 acc[4][4];
#pragma unroll
    for (int mi = 0; mi < 4; ++mi)
#pragma unroll
        for (int ni = 0; ni < 4; ++ni) acc[mi][ni] = zero;

    int sr = t >> 3;
    int c8 = (t & 7) * 8;

    for (int k0 = 0; k0 < K; k0 += 64) {
        __syncthreads();
        if (NORMA) {
            float scj[8], shj[8];
            if (Sa) {
#pragma unroll
                for (int j = 0; j < 8; ++j) {
                    int ch = k0 + c8 + j;
                    float mean = Sa[ch] * (1.f / 8192.f);
                    float var = Qa[ch] * (1.f / 8192.f) - mean * mean;
                    float rs = rsqrtf(var + EPSV);
                    scj[j] = ga[ch] * rs;
                    shj[j] = ba[ch] - mean * scj[j];
                }
            } else {
#pragma unroll
                for (int j = 0; j < 8; ++j) { scj[j] = 1.f; shj[j] = 0.f; }
            }
#pragma unroll
            for (int p = 0; p < 4; ++p) {
                int row = sr + p * 32;
                const float* src = (const float*)Ain + (size_t)(bm + row) * K + k0 + c8;
                float4 a0 = *(const float4*)src;
                float4 a1 = *(const float4*)(src + 4);
                union { u16 a[8]; int4 v; } pk;
                pk.a[0] = f2bf(a0.x * scj[0] + shj[0]);
                pk.a[1] = f2bf(a0.y * scj[1] + shj[1]);
                pk.a[2] = f2bf(a0.z * scj[2] + shj[2]);
                pk.a[3] = f2bf(a0.w * scj[3] + shj[3]);
                pk.a[4] = f2bf(a1.x * scj[4] + shj[4]);
                pk.a[5] = f2bf(a1.y * scj[5] + shj[5]);
                pk.a[6] = f2bf(a1.z * scj[6] + shj[6]);
                pk.a[7] = f2bf(a1.w * scj[7] + shj[7]);
                *(int4*)&As[row][SWZ(row, c8)] = pk.v;
            }
        } else {
#pragma unroll
            for (int p = 0; p < 4; ++p) {
                int row = sr + p * 32;
                const u16* src = (const u16*)Ain + (size_t)(bm + row) * K + k0 + c8;
                *(int4*)&As[row][SWZ(row, c8)] = *(const int4*)src;
            }
        }
#pragma unroll
        for (int p = 0; p < 4; ++p) {
            int row = sr + p * 32;
            const u16* srcW = W + (size_t)(bn + row) * K + k0 + c8;
            *(int4*)&Ws[row][SWZ(row, c8)] = *(const int4*)srcW;
        }
        __syncthreads();
#pragma unroll
        for (int kk = 0; kk < 2; ++kk) {
            bf16x8 af[4], bf[4];
#pragma unroll
            for (int mi = 0; mi < 4; ++mi) {
                int row = wr * 64 + mi * 16 + lr;
                af[mi] = *(const bf16x8*)&As[row][SWZ(row, kk * 32 + lg * 8)];
            }
#pragma unroll
            for (int ni = 0; ni < 4; ++ni) {
                int row = wc * 64 + ni * 16 + lr;
                bf[ni] = *(const bf16x8*)&Ws[row][SWZ(row, kk * 32 + lg * 8)];
            }
#pragma unroll
            for (int mi = 0; mi < 4; ++mi)
#pragma unroll
                for (int ni = 0; ni < 4; ++ni)
                    acc[mi][ni] = __builtin_amdgcn_mfma_f32_16x16x32_bf16(af[mi], bf[ni], acc[mi][ni], 0, 0, 0);
        }
    }

#pragma unroll
    for (int ni = 0; ni < 4; ++ni) {
        int col = bn + wc * 64 + ni * 16 + lr;
        float bj = bias ? bias[col] : 0.f;
#pragma unroll
        for (int mi = 0; mi < 4; ++mi) {
#pragma unroll
            for (int r = 0; r < 4; ++r) {
                int row = bm + wr * 64 + mi * 16 + lg * 4 + r;
                float v = acc[mi][ni][r] + bj;
                if (EPI == 1) v = gelu_erf(v);
                if (OUTBF)
                    ((u16*)Cout)[(size_t)row * N + col] = f2bf(v);
                else
                    ((float*)Cout)[(size_t)row * N + col] = v;
            }
        }
    }
}

// small K=8 GEMM accumulate: h += pe @ W_pe^T + b_pe (fp32 only)
__global__ __launch_bounds__(256) void pe_add_kernel(const float* __restrict__ pe,
                                                     const float* __restrict__ Wpe,
                                                     const float* __restrict__ bpe,
                                                     float* __restrict__ h) {
    __shared__ float Ws[8][256];
    int t = threadIdx.x;
    for (int i = t; i < 2048; i += 256) Ws[i & 7][i >> 3] = Wpe[i];
    __syncthreads();
    int w = t >> 6, lane = t & 63;
    int r = blockIdx.x * 4 + w;
    const float* pr = pe + r * 8;
    float p[8];
#pragma unroll
    for (int k = 0; k < 8; ++k) p[k] = pr[k];
    int c0 = lane * 4;
    float4 hv = *(float4*)&h[(size_t)r * HH + c0];
    float o0 = hv.x + bpe[c0 + 0], o1 = hv.y + bpe[c0 + 1];
    float o2 = hv.z + bpe[c0 + 2], o3 = hv.w + bpe[c0 + 3];
#pragma unroll
    for (int k = 0; k < 8; ++k) {
        o0 += p[k] * Ws[k][c0 + 0];
        o1 += p[k] * Ws[k][c0 + 1];
        o2 += p[k] * Ws[k][c0 + 2];
        o3 += p[k] * Ws[k][c0 + 3];
    }
    float4 ov; ov.x = o0; ov.y = o1; ov.z = o2; ov.w = o3;
    *(float4*)&h[(size_t)r * HH + c0] = ov;
}

// ---------------- V transpose: qkv V-part -> vT[b][h][d][key] ----------------
__global__ __launch_bounds__(256) void vtrans_kernel(const u16* __restrict__ qkv,
                                                     u16* __restrict__ vT) {
    __shared__ u16 Ls[64][64];
    int bid = blockIdx.x;
    int kt = bid & 15;
    int head = (bid >> 4) & 7;
    int b = bid >> 7;
    int t = threadIdx.x;
    int key_l = t >> 2, blkS = t & 3;
    const u16* src = qkv + (size_t)(b * NN + kt * 64 + key_l) * 768 + 512 + head * DH + blkS * 8;
    int sb = (blkS ^ (key_l & 7) ^ ((key_l >> 3) & 7)) * 8;
    *(int4*)&Ls[key_l][sb] = *(const int4*)src;
    __syncthreads();
    int d = t >> 3, kc = t & 7;
    union { u16 a[8]; int4 v; } tmp;
#pragma unroll
    for (int j = 0; j < 8; ++j) {
        int col = (((d >> 3) ^ j ^ kc) << 3) | (d & 7);
        tmp.a[j] = Ls[kc * 8 + j][col];
    }
    u16* dst = vT + (size_t)((b * 8 + head) * 32 + d) * NN + kt * 64 + kc * 8;
    *(int4*)dst = tmp.v;
}

// ---------------- MFMA flash attention (exp2-domain softmax, defer-max) ------
__global__ __launch_bounds__(256) void attn_mfma_kernel(const u16* __restrict__ qkv,
                                                        const u16* __restrict__ vT,
                                                        u16* __restrict__ o) {
    __shared__ __align__(16) u16 Ks[64][40];
    __shared__ __align__(16) u16 Vt[32][72];
    __shared__ __align__(16) u16 Ot[64][40];
    int bid = blockIdx.x;
    int qt = bid & 15;
    int head = (bid >> 4) & 7;
    int b = bid >> 7;
    int t = threadIdx.x;
    int w = t >> 6, lane = t & 63;
    int lr = lane & 15, lg = lane >> 4;

    // q scale = 1/sqrt(32) * log2(e)  (exp2-domain softmax)
    bf16x8 qf;
    {
        const u16* qsrc = qkv + (size_t)(b * NN + qt * 64 + w * 16 + lr) * 768 + head * DH + lg * 8;
        bf16x8 raw = *(const bf16x8*)qsrc;
#pragma unroll
        for (int j = 0; j < 8; ++j) {
            float f = bf2f((u16)raw[j]) * 0.25503530f;
            qf[j] = (short)f2bf(f);
        }
    }

    f32x4 zero = {0.f, 0.f, 0.f, 0.f};
    f32x4 oacc[2] = {zero, zero};
    float m = -1e30f, l = 0.f;

    int srow = t >> 2, sc8 = (t & 3) * 8;
    int vd = t >> 3, vc8 = (t & 7) * 8;
    const u16* kbase = qkv + (size_t)(b * NN) * 768 + 256 + head * DH + sc8;
    const u16* vbase = vT + (size_t)((b * 8 + head) * 32 + vd) * NN + vc8;

    int srcA = ((lg & 1) << 5) + lr;
    int srcB = srcA + 16;
    int hi = lg >> 1;

    for (int k0 = 0; k0 < NN; k0 += 64) {
        __syncthreads();
        *(int4*)&Ks[srow][sc8] = *(const int4*)(kbase + (size_t)(k0 + srow) * 768);
        *(int4*)&Vt[vd][vc8] = *(const int4*)(vbase + k0);
        __syncthreads();

        f32x4 st[4];
#pragma unroll
        for (int kt = 0; kt < 4; ++kt) {
            bf16x8 kf = *(const bf16x8*)&Ks[kt * 16 + lr][lg * 8];
            st[kt] = __builtin_amdgcn_mfma_f32_16x16x32_bf16(kf, qf, zero, 0, 0, 0);
        }

        float tm = -1e30f;
#pragma unroll
        for (int kt = 0; kt < 4; ++kt)
#pragma unroll
            for (int r = 0; r < 4; ++r) tm = fmaxf(tm, st[kt][r]);
        tm = fmaxf(tm, __shfl_xor(tm, 16));
        tm = fmaxf(tm, __shfl_xor(tm, 32));
        // defer-max (T13): rescale only when max grows by >8 (log2 units; P <= 256)
        if (__any(tm > m + 8.0f)) {
            float mn = fmaxf(m, tm);
            float corr = exp2_fast(m - mn);
            l *= corr;
#pragma unroll
            for (int dh = 0; dh < 2; ++dh)
#pragma unroll
                for (int r = 0; r < 4; ++r) oacc[dh][r] *= corr;
            m = mn;
        }

        float ps = 0.f;
        u32 pw0[4], pw1[4];
#pragma unroll
        for (int kt = 0; kt < 4; ++kt) {
            float p0 = exp2_fast(st[kt][0] - m);
            float p1 = exp2_fast(st[kt][1] - m);
            float p2 = exp2_fast(st[kt][2] - m);
            float p3 = exp2_fast(st[kt][3] - m);
            ps += (p0 + p1) + (p2 + p3);
            pw0[kt] = pack2bf(p0, p1);
            pw1[kt] = pack2bf(p2, p3);
        }
        ps += __shfl_xor(ps, 16);
        ps += __shfl_xor(ps, 32);
        l += ps;

#pragma unroll
        for (int c = 0; c < 2; ++c) {
            u32 w0a = (u32)__shfl((int)pw0[c * 2], srcA);
            u32 w0b = (u32)__shfl((int)pw0[c * 2 + 1], srcA);
            u32 w1a = (u32)__shfl((int)pw1[c * 2], srcA);
            u32 w1b = (u32)__shfl((int)pw1[c * 2 + 1], srcA);
            u32 w2a = (u32)__shfl((int)pw0[c * 2], srcB);
            u32 w2b = (u32)__shfl((int)pw0[c * 2 + 1], srcB);
            u32 w3a = (u32)__shfl((int)pw1[c * 2], srcB);
            u32 w3b = (u32)__shfl((int)pw1[c * 2 + 1], srcB);
            union { bf16x8 v; u32 u[4]; } pf;
            pf.u[0] = hi ? w0b : w0a;
            pf.u[1] = hi ? w1b : w1a;
            pf.u[2] = hi ? w2b : w2a;
            pf.u[3] = hi ? w3b : w3a;
#pragma unroll
            for (int dh = 0; dh < 2; ++dh) {
                bf16x8 vf = *(const bf16x8*)&Vt[dh * 16 + lr][c * 32 + lg * 8];
                oacc[dh] = __builtin_amdgcn_mfma_f32_16x16x32_bf16(vf, pf.v, oacc[dh], 0, 0, 0);
            }
        }
    }

    float inv = 1.f / l;
    __syncthreads();
#pragma unroll
    for (int dh = 0; dh < 2; ++dh)
#pragma unroll
        for (int r = 0; r < 4; ++r)
            Ot[w * 16 + lr][dh * 16 + lg * 4 + r] = f2bf(oacc[dh][r] * inv);
    __syncthreads();
    {
        int orow = t >> 2, oc8 = (t & 3) * 8;
        u16* dst = o + (size_t)(b * NN + qt * 64 + orow) * HH + head * DH + oc8;
        *(int4*)dst = *(const int4*)&Ot[orow][oc8];
    }
}

// ---------------- head2 ----------------
__global__ __launch_bounds__(256) void head2_kernel(const float* __restrict__ g1,
                                                    const float* __restrict__ W2,
                                                    const float* __restrict__ b2,
                                                    float* __restrict__ out) {
    __shared__ float w[128];
    int t = threadIdx.x;
    if (t < 128) w[t] = W2[t];
    __syncthreads();
    int r = blockIdx.x * 256 + t;
    float s = b2[0];
    const float* row = g1 + (size_t)r * 128;
#pragma unroll
    for (int k = 0; k < 128; k += 4) {
        float4 v = *(const float4*)&row[k];
        s += v.x * w[k] + v.y * w[k + 1] + v.z * w[k + 2] + v.w * w[k + 3];
    }
    out[r] = 1.f / (1.f + __expf(-s));
}

extern "C" void kernel_launch(void* const* d_in, const int* in_sizes, int n_in,
                              void* d_out, int out_size, void* d_ws, size_t ws_size,
                              hipStream_t stream) {
    const float* x        = (const float*)d_in[0];
    const int*   edge_row = (const int*)d_in[1];
    const int*   edge_col = (const int*)d_in[2];
    const float* edge_val = (const float*)d_in[3];
    const float* pe       = (const float*)d_in[4];
    const float* W_in     = (const float*)d_in[5];
    const float* b_in     = (const float*)d_in[6];
    const float* W_pe     = (const float*)d_in[7];
    const float* b_pe     = (const float*)d_in[8];
    const float* gcn_W    = (const float*)d_in[9];
    const float* attn_in_W  = (const float*)d_in[10];
    const float* attn_in_b  = (const float*)d_in[11];
    const float* attn_out_W = (const float*)d_in[12];
    const float* attn_out_b = (const float*)d_in[13];
    const float* bn_g     = (const float*)d_in[14];
    const float* bn_b     = (const float*)d_in[15];
    const float* ffn_W1   = (const float*)d_in[16];
    const float* ffn_b1   = (const float*)d_in[17];
    const float* ffn_W2   = (const float*)d_in[18];
    const float* ffn_b2   = (const float*)d_in[19];
    const float* head_W1  = (const float*)d_in[20];
    const float* head_b1  = (const float*)d_in[21];
    const float* head_W2  = (const float*)d_in[22];
    const float* head_b2  = (const float*)d_in[23];
    float* out = (float*)d_out;

    float* w = (float*)d_ws;
    float* h    = w; w += 2097152;       // (8192,256) fp32 residual stream (pre-norm)
    float* buf1 = w; w += 8388608;       // 32MB multi-use
    float* buf2 = w; w += 2097152;       // gather gelu output (8MB)
    int* counts    = (int*)w; w += 8192; // zeroed by memset
    float* bnstats = w; w += 1024;       // [2 slots][S 256 | Q 256], zeroed by same memset
    int* row_start = (int*)w; w += 8224;
    int* cursor    = (int*)w; w += 8192;
    int* csr_e     = (int*)w; w += 131072;
    // bf16 region
    u16* xb   = (u16*)w;
    u16* aob  = xb + 1048576;
    u16* wbWin = aob + 2097152;
    u16* wbGcn = wbWin + 32768;
    u16* wbAin = wbGcn + 262144;
    u16* wbAout = wbAin + 786432;
    u16* wbF1  = wbAout + 262144;
    u16* wbF2  = wbF1 + 1048576;
    u16* wbH1  = wbF2 + 1048576;
    // aliases inside buf1 (time-disjoint)
    u16* t1b  = (u16*)buf1;
    u16* qkvb = (u16*)buf1;
    u16* midb = (u16*)buf1;
    u16* vT   = (u16*)buf1 + 12582912;

    auto Sp = [&](int k) { return bnstats + (k & 1) * 512; };
    auto Qp = [&](int k) { return bnstats + (k & 1) * 512 + 256; };
    const float* NF = nullptr;

    // CSR build (+ zero both BN stats slots via the same memset)
    hipMemsetAsync(counts, 0, (8192 + 1024) * sizeof(int), stream);
    hist_kernel<<<512, 256, 0, stream>>>(edge_row, counts);
    prefix_kernel<<<1, 256, 0, stream>>>(counts, row_start, cursor);
    scatter_kernel<<<512, 256, 0, stream>>>(edge_row, cursor, csr_e);

    // all weight/x casts in one launch
    cast_all_kernel<<<4416, 256, 0, stream>>>(
        x, W_in, gcn_W, attn_in_W, attn_out_W, ffn_W1, ffn_W2, head_W1,
        xb, wbWin, wbGcn, wbAin, wbAout, wbF1, wbF2, wbH1);

    // input projection (bf16 A, fp32 out -> h) + PE add
    gemm_mfma<0, 0, 0><<<dim3(4, 64), 256, 0, stream>>>(xb, wbWin, b_in, h, BN, D_IN, HH,
        NF, NF, NF, NF, NF, NF, NF, NF, nullptr, nullptr, nullptr, nullptr);
    pe_add_kernel<<<2048, 256, 0, stream>>>(pe, W_pe, b_pe, h);

    for (int l = 0; l < LL; ++l) {
        int k1 = 3 * l, k2 = 3 * l + 1, k3 = 3 * l + 2;
        const float* SaP = (l == 0) ? nullptr : Sp(k1 - 1);
        const float* QaP = (l == 0) ? nullptr : Qp(k1 - 1);
        const float* gP  = (l == 0) ? bn_g : bn_g + (k1 - 1) * 256;
        const float* bP  = (l == 0) ? bn_b : bn_b + (k1 - 1) * 256;

        // GCN linear: t1b = norm_{BN(k1-1)}(h) @ gcn_W^T (bf16 out); zeroes slot k1
        gemm_mfma<0, 1, 1><<<dim3(4, 64), 256, 0, stream>>>(h, wbGcn + l * 65536, nullptr, t1b, BN, HH, HH,
            SaP, QaP, gP, bP, NF, NF, NF, NF, nullptr, nullptr, Sp(k1), Qp(k1));
        // gather (wave-per-row, fast) -> buf2 ; then fused norm+residual+stats
        gcn_gather_kernel<<<2048, 256, 0, stream>>>(t1b, row_start, csr_e, edge_col, edge_val, buf2);
        bn_reduce_norm_kernel<<<256, 256, 0, stream>>>(h, buf2, SaP, QaP, gP, bP, Sp(k1), Qp(k1));

        // qkv = norm_{BN(k1)}(h) @ Wqkv^T (bf16); zeroes slot k2
        gemm_mfma2<0, 1, 1><<<dim3(6, 64), 256, 0, stream>>>(h, wbAin + l * 196608, attn_in_b + l * 768, qkvb, BN, HH, 768,
            Sp(k1), Qp(k1), bn_g + k1 * 256, bn_b + k1 * 256, Sp(k2), Qp(k2));
        vtrans_kernel<<<1024, 256, 0, stream>>>(qkvb, vT);
        attn_mfma_kernel<<<1024, 256, 0, stream>>>(qkvb, vT, aob);
        // out-proj: h = norm_{BN(k1)}(h) + aob @ Waout^T + b ; accumulates BN(k2) stats
        gemm_mfma<0, 2, 0><<<dim3(4, 64), 256, 0, stream>>>(aob, wbAout + l * 65536, attn_out_b + l * 256, h, BN, HH, HH,
            NF, NF, NF, NF, Sp(k1), Qp(k1), bn_g + k1 * 256, bn_b + k1 * 256, Sp(k2), Qp(k2), nullptr, nullptr);

        // FFN: mid = gelu(norm_{BN(k2)}(h) @ W1^T) (bf16); zeroes slot k3
        gemm_mfma2<1, 1, 1><<<dim3(8, 64), 256, 0, stream>>>(h, wbF1 + l * 262144, ffn_b1 + l * 1024, midb, BN, HH, 1024,
            Sp(k2), Qp(k2), bn_g + k2 * 256, bn_b + k2 * 256, Sp(k3), Qp(k3));
        // ffn2: h = norm_{BN(k2)}(h) + mid @ W2^T + b ; accumulates BN(k3) stats
        gemm_mfma<0, 2, 0><<<dim3(4, 64), 256, 0, stream>>>(midb, wbF2 + l * 262144, ffn_b2 + l * 256, h, BN, 1024, HH,
            NF, NF, NF, NF, Sp(k2), Qp(k2), bn_g + k2 * 256, bn_b + k2 * 256, Sp(k3), Qp(k3), nullptr, nullptr);
    }

    // head: g1 = gelu(norm_{BN11}(h) @ head_W1^T) fp32 ; out = sigmoid(g1 @ W2^T + b2)
    gemm_mfma<1, 0, 1><<<dim3(2, 64), 256, 0, stream>>>(h, wbH1, head_b1, buf1, BN, HH, 128,
        Sp(11), Qp(11), bn_g + 11 * 256, bn_b + 11 * 256, NF, NF, NF, NF, nullptr, nullptr, nullptr, nullptr);
    head2_kernel<<<32, 256, 0, stream>>>(buf1, head_W2, head_b2, out);
}